// Round 3
// baseline (536.706 us; speedup 1.0000x reference)
//
#include <hip/hip_runtime.h>
#include <hip/hip_bf16.h>
#include <hip/hip_fp16.h>
#include <math.h>

#define Bn 32
#define CL 1024
#define QL 128
#define Hh 512
#define NEGV (-1e30f)

typedef short bf16x8 __attribute__((ext_vector_type(8)));
typedef float f32x4 __attribute__((ext_vector_type(4)));

__device__ inline unsigned short f2bf(float x) {
  union { float f; unsigned u; } v; v.f = x;
  unsigned r = v.u + 0x7fff + ((v.u >> 16) & 1);
  return (unsigned short)(r >> 16);
}
__device__ inline unsigned packbf(float x, float y) {
  return (unsigned)f2bf(x) | ((unsigned)f2bf(y) << 16);
}

// ---------------- prep_c: C16 = bf16(C), rc = C@w1 (fused, C read once) ----------
__global__ __launch_bounds__(256) void prep_c_kernel(
    const float* __restrict__ C, const float* __restrict__ w1,
    float* __restrict__ rc, unsigned short* __restrict__ C16) {
  int t = threadIdx.x;
  int row = blockIdx.x * 16 + (t >> 4);  // 16 rows per block
  int seg = t & 15;                      // 16 segs x 32 cols per row
  const float* x = C + (size_t)row * Hh + seg * 32;
  unsigned* y = (unsigned*)C16 + (size_t)row * (Hh / 2) + seg * 16;
  float s = 0.f;
  for (int q = 0; q < 4; ++q) {
    float4 v0 = *(const float4*)(x + q * 8);
    float4 v1 = *(const float4*)(x + q * 8 + 4);
    float4 w0 = *(const float4*)(w1 + seg * 32 + q * 8);
    float4 w1v = *(const float4*)(w1 + seg * 32 + q * 8 + 4);
    s += v0.x * w0.x + v0.y * w0.y + v0.z * w0.z + v0.w * w0.w;
    s += v1.x * w1v.x + v1.y * w1v.y + v1.z * w1v.z + v1.w * w1v.w;
    uint4 st;
    st.x = packbf(v0.x, v0.y); st.y = packbf(v0.z, v0.w);
    st.z = packbf(v1.x, v1.y); st.w = packbf(v1.z, v1.w);
    *(uint4*)(y + q * 4) = st;
  }
  for (int off = 1; off < 16; off <<= 1) s += __shfl_xor(s, off, 64);
  if (seg == 0) rc[row] = s;
}

// ---------------- rowdot (Q only): cq[r] = dot(Q[r,:], w2) + b ----------------
__global__ __launch_bounds__(256) void rowdot_kernel(
    const float* __restrict__ X, const float* __restrict__ w,
    const float* __restrict__ bias, float* __restrict__ out, int nrows) {
  int row = blockIdx.x * 4 + (threadIdx.x >> 6);
  int lane = threadIdx.x & 63;
  if (row >= nrows) return;
  const float* x = X + (size_t)row * Hh;
  float s = 0.f;
  for (int h = lane; h < Hh; h += 64) s += x[h] * w[h];
  for (int off = 32; off > 0; off >>= 1) s += __shfl_down(s, off, 64);
  if (lane == 0) out[row] = s + (bias ? bias[0] : 0.f);
}

// ---------------- prep_q: Qs = bf16(Q*w3) [j][h], QT = bf16(Q^T) [h][j] ----------
__global__ __launch_bounds__(256) void prep_q_kernel(
    const float* __restrict__ Q, const float* __restrict__ w3,
    unsigned short* __restrict__ Qs, unsigned short* __restrict__ QT) {
  __shared__ float tile[QL * 65];  // [j][64 h]
  int b = blockIdx.y, h0 = blockIdx.x * 64, t = threadIdx.x;
  const float* Qb = Q + (size_t)b * QL * Hh;
  unsigned* Qsu = (unsigned*)Qs + (size_t)b * QL * (Hh / 2);
  unsigned* QTu = (unsigned*)QT + ((size_t)b * Hh + h0) * (QL / 2);
  for (int l = 0; l < 16; ++l) {
    int idx = t + l * 256; int c = idx & 31, j = idx >> 5;
    float2 v = *(const float2*)(Qb + (size_t)j * Hh + h0 + 2 * c);
    float wa = w3[h0 + 2 * c], wb = w3[h0 + 2 * c + 1];
    Qsu[(size_t)j * (Hh / 2) + h0 / 2 + c] = packbf(v.x * wa, v.y * wb);
    tile[j * 65 + 2 * c] = v.x;
    tile[j * 65 + 2 * c + 1] = v.y;
  }
  __syncthreads();
  for (int l = 0; l < 16; ++l) {
    int idx = t + l * 256; int jc = idx & 63, h = idx >> 6;
    QTu[(size_t)h * (QL / 2) + jc] =
        packbf(tile[(2 * jc) * 65 + h], tile[(2 * jc + 1) * 65 + h]);
  }
}

// ---- S = C16@(Qs)^T + rc + cq; row softmax -> Prow bf16 + S16 fp16 + col partials ----
__global__ __launch_bounds__(256) void s_mfma_kernel(
    const unsigned short* __restrict__ C16, const unsigned short* __restrict__ Qs,
    const int* __restrict__ Qmask, const int* __restrict__ Cmask,
    const float* __restrict__ rc, const float* __restrict__ cq,
    unsigned short* __restrict__ S16, unsigned short* __restrict__ Prow,
    float* __restrict__ partm, float* __restrict__ partl) {
  __shared__ unsigned sA[64 * 32];   // 64 i x 64 k bf16 (swizzled)
  __shared__ unsigned sB[128 * 32];  // 128 j x 64 k bf16 (swizzled)
  __shared__ int qm[QL];
  __shared__ int cmk[64];
  __shared__ float swm[4 * QL], swl[4 * QL];
  int b = blockIdx.y, i0 = blockIdx.x * 64, t = threadIdx.x;
  if (t < QL) qm[t] = Qmask[b * QL + t];
  if (t >= 128 && t < 192) cmk[t - 128] = Cmask[b * CL + i0 + (t - 128)];
  __syncthreads();
  int lane = t & 63, w = t >> 6;
  int lanen = lane & 15, quad = lane >> 4;
  int c = t & 31, rA = t >> 5;
  f32x4 acc[8];
  for (int nt = 0; nt < 8; ++nt) acc[nt] = (f32x4){0.f, 0.f, 0.f, 0.f};
  const unsigned* Cu = (const unsigned*)C16 + ((size_t)b * CL + i0) * (Hh / 2);
  const unsigned* Qu = (const unsigned*)Qs + (size_t)b * QL * (Hh / 2);
  for (int k0 = 0; k0 < Hh / 2; k0 += 32) {  // 8 iters, BK=64 bf16
    for (int l = 0; l < 8; ++l) {            // A copy: 64x32 u32
      int rr = rA + l * 8;
      sA[rr * 32 + (c ^ ((rr & 7) << 2))] = Cu[(size_t)rr * (Hh / 2) + k0 + c];
    }
    for (int l = 0; l < 16; ++l) {           // B copy: 128x32 u32
      int idx = t + l * 256; int cc = idx & 31, j = idx >> 5;
      sB[j * 32 + (cc ^ ((j & 7) << 2))] = Qu[(size_t)j * (Hh / 2) + k0 + cc];
    }
    __syncthreads();
    for (int kk = 0; kk < 2; ++kk) {
      int arow = w * 16 + lanen;
      bf16x8 a = *(const bf16x8*)(sA + arow * 32 + ((kk * 16 + quad * 4) ^ ((arow & 7) << 2)));
      for (int nt = 0; nt < 8; ++nt) {
        int brow = nt * 16 + lanen;
        bf16x8 bb = *(const bf16x8*)(sB + brow * 32 + ((kk * 16 + quad * 4) ^ ((brow & 7) << 2)));
        acc[nt] = __builtin_amdgcn_mfma_f32_16x16x32_bf16(a, bb, acc[nt], 0, 0, 0);
      }
    }
    __syncthreads();
  }
  float cqv[8]; int qmv[8];
  for (int nt = 0; nt < 8; ++nt) {
    int j = nt * 16 + lanen;
    cqv[nt] = cq[b * QL + j]; qmv[nt] = qm[j];
  }
  float colM[8], colL[8];
  for (int nt = 0; nt < 8; ++nt) { colM[nt] = -INFINITY; colL[nt] = 0.f; }
  int rowbase = i0 + w * 16 + quad * 4;
  for (int r = 0; r < 4; ++r) {
    int row = rowbase + r;
    float rcv = rc[b * CL + row];
    int cmr = cmk[w * 16 + quad * 4 + r];
    float vals[8], mv = -INFINITY;
    for (int nt = 0; nt < 8; ++nt) {
      float val = acc[nt][r] + rcv + cqv[nt];
      vals[nt] = val;
      mv = fmaxf(mv, qmv[nt] ? val : NEGV);
    }
    for (int off = 1; off < 16; off <<= 1) mv = fmaxf(mv, __shfl_xor(mv, off, 64));
    float ls = 0.f;
    for (int nt = 0; nt < 8; ++nt) ls += __expf((qmv[nt] ? vals[nt] : NEGV) - mv);
    for (int off = 1; off < 16; off <<= 1) ls += __shfl_xor(ls, off, 64);
    float linv = 1.f / ls;
    size_t base = ((size_t)b * CL + row) * QL;
    for (int nt = 0; nt < 8; ++nt) {
      int j = nt * 16 + lanen;
      S16[base + j] = __half_as_ushort(__float2half(vals[nt]));
      Prow[base + j] = f2bf(__expf((qmv[nt] ? vals[nt] : NEGV) - mv) * linv);
      float v = cmr ? vals[nt] : NEGV;
      float nm = fmaxf(colM[nt], v);
      colL[nt] = colL[nt] * __expf(colM[nt] - nm) + __expf(v - nm);
      colM[nt] = nm;
    }
  }
  for (int off = 16; off <= 32; off <<= 1) {
    for (int nt = 0; nt < 8; ++nt) {
      float m2 = __shfl_xor(colM[nt], off, 64);
      float l2 = __shfl_xor(colL[nt], off, 64);
      float nm = fmaxf(colM[nt], m2);
      colL[nt] = colL[nt] * __expf(colM[nt] - nm) + l2 * __expf(m2 - nm);
      colM[nt] = nm;
    }
  }
  if (quad == 0) {
    for (int nt = 0; nt < 8; ++nt) {
      swm[w * QL + nt * 16 + lanen] = colM[nt];
      swl[w * QL + nt * 16 + lanen] = colL[nt];
    }
  }
  __syncthreads();
  if (t < QL) {
    float m = -INFINITY, L = 0.f;
    for (int ww = 0; ww < 4; ++ww) {
      float m2 = swm[ww * QL + t], l2 = swl[ww * QL + t];
      float nm = fmaxf(m, m2);
      L = L * __expf(m - nm) + l2 * __expf(m2 - nm);
      m = nm;
    }
    partm[((size_t)b * 16 + blockIdx.x) * QL + t] = m;
    partl[((size_t)b * 16 + blockIdx.x) * QL + t] = L;
  }
}

// ---------------- column softmax stats, stage 2 ----------------
__global__ __launch_bounds__(128) void colstat2_kernel(
    const float* __restrict__ partm, const float* __restrict__ partl,
    float* __restrict__ colm, float* __restrict__ colinv) {
  int b = blockIdx.x, j = threadIdx.x;
  float m = -INFINITY, L = 0.f;
  for (int c = 0; c < 16; ++c) {
    float m2 = partm[(b * 16 + c) * QL + j], l2 = partl[(b * 16 + c) * QL + j];
    float nm = fmaxf(m, m2);
    L = L * __expf(m - nm) + l2 * __expf(m2 - nm);
    m = nm;
  }
  colm[b * QL + j] = m;
  colinv[b * QL + j] = 1.f / L;
}

// ---------------- P_col^T bf16 [b][j][i] from S16 fp16 ----------------
__global__ __launch_bounds__(256) void pcol_kernel(
    const unsigned short* __restrict__ S16, const int* __restrict__ Cmask,
    const float* __restrict__ colm, const float* __restrict__ colinv,
    unsigned short* __restrict__ PT) {
  __shared__ unsigned short tile[64 * 130];
  __shared__ int cm[64];
  __shared__ float cmj[QL], civ[QL];
  int b = blockIdx.y, i0 = blockIdx.x * 64, t = threadIdx.x;
  if (t < 64) cm[t] = Cmask[b * CL + i0 + t];
  if (t >= 128) { int j = t - 128; cmj[j] = colm[b * QL + j]; civ[j] = colinv[b * QL + j]; }
  __syncthreads();
  const unsigned* Su = (const unsigned*)S16 + ((size_t)b * CL + i0) * (QL / 2);
  for (int l = 0; l < 16; ++l) {
    int idx = t + l * 256; int jc = idx & 63, il = idx >> 6;
    unsigned v = Su[(size_t)il * 64 + jc];
    int j0 = jc * 2;
    float v0 = cm[il] ? __half2float(__ushort_as_half((unsigned short)(v & 0xffff))) : NEGV;
    float v1 = cm[il] ? __half2float(__ushort_as_half((unsigned short)(v >> 16))) : NEGV;
    tile[il * 130 + j0]     = f2bf(__expf(v0 - cmj[j0]) * civ[j0]);
    tile[il * 130 + j0 + 1] = f2bf(__expf(v1 - cmj[j0 + 1]) * civ[j0 + 1]);
  }
  __syncthreads();
  unsigned* PTu = (unsigned*)PT;
  for (int l = 0; l < 16; ++l) {
    int idx = t + l * 256; int ci = idx & 31, j = idx >> 5;
    PTu[(((size_t)b * QL + j) * CL + i0) / 2 + ci] =
        (unsigned)tile[(2 * ci) * 130 + j] | ((unsigned)tile[(2 * ci + 1) * 130 + j] << 16);
  }
}

// ---------------- TT[h][j] = sum_i C16^T[h,i] * Pcol[i,j]  (bf16 out) ----------------
__global__ __launch_bounds__(256) void t_mfma_kernel(
    const unsigned short* __restrict__ C16, const unsigned short* __restrict__ PT,
    unsigned short* __restrict__ TT) {
  __shared__ unsigned ct[64 * 17];   // [64 i][16 u32 = 32 h] bf16 pairs along h
  __shared__ unsigned sA[32 * 32];   // [32 h][64 i] bf16 (swizzled)
  __shared__ unsigned sB[128 * 32];  // [128 j][64 i] bf16 (swizzled)
  int b = blockIdx.y, h0 = blockIdx.x * 32, t = threadIdx.x;
  int lane = t & 63, w = t >> 6;
  int lanen = lane & 15, quad = lane >> 4;
  int mw = w >> 1, nw = w & 1;
  f32x4 acc[4];
  for (int nt = 0; nt < 4; ++nt) acc[nt] = (f32x4){0.f, 0.f, 0.f, 0.f};
  const unsigned* Cu = (const unsigned*)C16 + (size_t)b * CL * (Hh / 2) + h0 / 2;
  const unsigned* PTu = (const unsigned*)PT + (size_t)b * QL * (CL / 2);
  const unsigned short* ct16 = (const unsigned short*)ct;
  for (int i0 = 0; i0 < CL; i0 += 64) {   // 16 iters, BK=64
    for (int l = 0; l < 4; ++l) {         // C16 tile [64 i][16 u32]
      int idx = t + l * 256; int hc = idx & 15, ii = idx >> 4;
      ct[ii * 17 + hc] = Cu[(size_t)(i0 + ii) * (Hh / 2) + hc];
    }
    for (int l = 0; l < 16; ++l) {        // PT tile [128 j][32 u32]
      int idx = t + l * 256; int c2 = idx & 31, j = idx >> 5;
      sB[j * 32 + (c2 ^ ((j & 7) << 2))] = PTu[(size_t)j * (CL / 2) + i0 / 2 + c2];
    }
    __syncthreads();
    for (int l = 0; l < 4; ++l) {         // transpose-pack: sA[h][i-pair]
      int idx = t + l * 256; int c2 = idx & 31, hh = idx >> 5;
      unsigned lo = ct16[(2 * c2) * 34 + hh];
      unsigned hi = ct16[(2 * c2 + 1) * 34 + hh];
      sA[hh * 32 + (c2 ^ ((hh & 7) << 2))] = lo | (hi << 16);
    }
    __syncthreads();
    for (int kk = 0; kk < 2; ++kk) {
      int arow = mw * 16 + lanen;
      bf16x8 a = *(const bf16x8*)(sA + arow * 32 + ((kk * 16 + quad * 4) ^ ((arow & 7) << 2)));
      for (int nt = 0; nt < 4; ++nt) {
        int brow = nw * 64 + nt * 16 + lanen;
        bf16x8 bb = *(const bf16x8*)(sB + brow * 32 + ((kk * 16 + quad * 4) ^ ((brow & 7) << 2)));
        acc[nt] = __builtin_amdgcn_mfma_f32_16x16x32_bf16(a, bb, acc[nt], 0, 0, 0);
      }
    }
    __syncthreads();
  }
  for (int nt = 0; nt < 4; ++nt)
    for (int r = 0; r < 4; ++r) {
      int h = h0 + mw * 16 + quad * 4 + r;
      int j = nw * 64 + nt * 16 + lanen;
      TT[((size_t)b * Hh + h) * QL + j] = f2bf(acc[nt][r]);
    }
}

// ---- out: A = P@Q, Bm = P@T; single K=128 phase, LDS-staged coalesced epilogue ----
__global__ __launch_bounds__(256) void out_mfma_kernel(
    const unsigned short* __restrict__ Prow, const unsigned short* __restrict__ TT,
    const unsigned short* __restrict__ QT, const float* __restrict__ C,
    float* __restrict__ out) {
  __shared__ unsigned smem[3 * 64 * 64];  // 48 KB: staging sP/sQ/sT, reused as epilogue f32
  unsigned* sP = smem;
  unsigned* sQ = smem + 64 * 64;
  unsigned* sT = smem + 2 * 64 * 64;
  int b = blockIdx.z, i0 = blockIdx.y * 64, h0 = blockIdx.x * 64, t = threadIdx.x;
  int lane = t & 63, w = t >> 6;
  int lanen = lane & 15, quad = lane >> 4;
  const unsigned* Pu = (const unsigned*)Prow + ((size_t)b * CL + i0) * (QL / 2);
  const unsigned* Tu = (const unsigned*)TT + ((size_t)b * Hh + h0) * (QL / 2);
  const unsigned* Qu = (const unsigned*)QT + ((size_t)b * Hh + h0) * (QL / 2);
  for (int l = 0; l < 16; ++l) {
    int idx = t + l * 256; int c = idx & 63, rr = idx >> 6;
    int cs = c ^ ((rr & 7) << 2);
    sP[rr * 64 + cs] = Pu[(size_t)rr * 64 + c];
    sQ[rr * 64 + cs] = Qu[(size_t)rr * 64 + c];
    sT[rr * 64 + cs] = Tu[(size_t)rr * 64 + c];
  }
  __syncthreads();
  f32x4 accA[4], accB[4];
  for (int nt = 0; nt < 4; ++nt) {
    accA[nt] = (f32x4){0.f, 0.f, 0.f, 0.f};
    accB[nt] = (f32x4){0.f, 0.f, 0.f, 0.f};
  }
  for (int kk = 0; kk < 4; ++kk) {
    int arow = w * 16 + lanen;
    bf16x8 a = *(const bf16x8*)(sP + arow * 64 + ((kk * 16 + quad * 4) ^ ((arow & 7) << 2)));
    for (int nt = 0; nt < 4; ++nt) {
      int brow = nt * 16 + lanen;
      int boff = brow * 64 + ((kk * 16 + quad * 4) ^ ((brow & 7) << 2));
      bf16x8 bq = *(const bf16x8*)(sQ + boff);
      bf16x8 bt = *(const bf16x8*)(sT + boff);
      accA[nt] = __builtin_amdgcn_mfma_f32_16x16x32_bf16(a, bq, accA[nt], 0, 0, 0);
      accB[nt] = __builtin_amdgcn_mfma_f32_16x16x32_bf16(a, bt, accB[nt], 0, 0, 0);
    }
  }
  __syncthreads();  // all waves done reading sP/sQ/sT before reuse
  float* fA = (float*)smem;             // 64x65 f32
  float* fB = (float*)smem + 64 * 65;   // 64x65 f32
  for (int nt = 0; nt < 4; ++nt)
    for (int r = 0; r < 4; ++r) {
      int iL = w * 16 + quad * 4 + r;
      int hL = nt * 16 + lanen;
      fA[iL * 65 + hL] = accA[nt][r];
      fB[iL * 65 + hL] = accB[nt][r];
    }
  __syncthreads();
  for (int rr = 0; rr < 16; ++rr) {
    int iL = w * 16 + rr;
    int i = i0 + iL;
    const float* Crow = C + ((size_t)b * CL + i) * Hh + h0;
    float* orow = out + ((size_t)b * CL + i) * (size_t)(4 * Hh) + h0;
    float cv = Crow[lane];
    float av = fA[iL * 65 + lane];
    float bv = fB[iL * 65 + lane];
    orow[lane] = cv;
    orow[Hh + lane] = av;
    orow[2 * Hh + lane] = cv * av;
    orow[3 * Hh + lane] = cv * bv;
  }
}

extern "C" void kernel_launch(void* const* d_in, const int* in_sizes, int n_in,
                              void* d_out, int out_size, void* d_ws, size_t ws_size,
                              hipStream_t stream) {
  const float* C = (const float*)d_in[0];
  const float* Q = (const float*)d_in[1];
  const int* Cmask = (const int*)d_in[2];
  const int* Qmask = (const int*)d_in[3];
  const float* w = (const float*)d_in[4];
  const float* bptr = (const float*)d_in[5];
  float* out = (float*)d_out;
  float* f = (float*)d_ws;

  // workspace layout: floats then ushorts
  float* rc     = f;            // 32768
  float* cq     = f + 32768;    // 4096
  float* colm   = f + 36864;    // 4096
  float* colinv = f + 40960;    // 4096
  float* partm  = f + 45056;    // 65536
  float* partl  = f + 110592;   // 65536
  unsigned short* u = (unsigned short*)(f + 176128);
  unsigned short* S16  = u;                  // 8 MB
  unsigned short* Prow = S16 + 4194304;      // 8 MB
  unsigned short* PT   = Prow + 4194304;     // 8 MB
  unsigned short* TT   = PT + 4194304;       // 4 MB
  unsigned short* QT   = TT + 2097152;       // 4 MB
  unsigned short* Qs   = QT + 2097152;       // 4 MB
  unsigned short* C16  = Qs + 2097152;       // 32 MB (total ~72 MB)

  prep_c_kernel<<<dim3((Bn * CL) / 16), 256, 0, stream>>>(C, w, rc, C16);
  rowdot_kernel<<<dim3((Bn * QL) / 4), 256, 0, stream>>>(Q, w + Hh, bptr, cq, Bn * QL);
  prep_q_kernel<<<dim3(Hh / 64, Bn), 256, 0, stream>>>(Q, w + 2 * Hh, Qs, QT);
  s_mfma_kernel<<<dim3(CL / 64, Bn), 256, 0, stream>>>(C16, Qs, Qmask, Cmask, rc, cq,
                                                       S16, Prow, partm, partl);
  colstat2_kernel<<<dim3(Bn), 128, 0, stream>>>(partm, partl, colm, colinv);
  pcol_kernel<<<dim3(CL / 64, Bn), 256, 0, stream>>>(S16, Cmask, colm, colinv, PT);
  t_mfma_kernel<<<dim3(Hh / 32, Bn), 256, 0, stream>>>(C16, PT, TT);
  out_mfma_kernel<<<dim3(Hh / 64, CL / 64, Bn), 256, 0, stream>>>(Prow, TT, QT, C, out);
}